// Round 3
// baseline (835.426 us; speedup 1.0000x reference)
//
#include <hip/hip_runtime.h>

// LSTM: B=1024, T=512, F=40, H=50, fp32. One SINGLE-WAVE block (64 threads)
// per batch element. Thread j owns ALL FOUR gate rows of hidden unit j
// (rows j, j+50, j+100, j+150), so:
//  - every LDS broadcast read of x_t / h feeds 16 FMAs (4x reuse vs r1/r2)
//  - the cell update is thread-local (c_j in a register) -> no pre-activation
//    LDS round trip and NO BARRIERS (wave-synchronous block).
// Weights: 368 floats/thread in registers; waves_per_eu(1,1) pins the
// unified VGPR+AGPR budget at 512/wave (1 wave/SIMD, 4 blocks/CU).

constexpr int kB = 1024;
constexpr int kT = 512;
constexpr int kF = 40;
constexpr int kH = 50;

__device__ __forceinline__ float fast_sigmoid(float v) {
    return __builtin_amdgcn_rcpf(1.f + __expf(-v));
}
__device__ __forceinline__ float fast_tanh(float v) {
    return 1.f - 2.f * __builtin_amdgcn_rcpf(__expf(2.f * v) + 1.f);
}

__global__ __attribute__((amdgpu_flat_work_group_size(64, 64),
                          amdgpu_waves_per_eu(1, 1)))
void lstm_unitwise(
    const float* __restrict__ x,      // [B,T,F]
    const float* __restrict__ W_ih,   // [4H,F]
    const float* __restrict__ W_hh,   // [4H,H]
    const float* __restrict__ b_ih,   // [4H]
    const float* __restrict__ b_hh,   // [4H]
    const float* __restrict__ W1,     // [10,H]
    const float* __restrict__ b1,     // [10]
    const float* __restrict__ W2,     // [1,10]
    const float* __restrict__ b2,     // [1]
    float* __restrict__ out)          // [B]
{
    const int b  = blockIdx.x;
    const int j  = threadIdx.x;                 // unit index for j < 50
    const int jj = (j < kH) ? j : (kH - 1);     // clamp lanes 50..63 (no OOB)

    __shared__ __align__(16) float sh_h[52];    // h state (50 + 2 pad)
    __shared__ __align__(16) float sh_x[2][40]; // double-buffered x_t
    __shared__ float sh_head[10];

    // Per-thread weights: 4 gate rows (i,f,g,o) of unit jj.
    float4 wih[4][10];   // W_ih[row, 0:40]
    float4 whh[4][13];   // W_hh[row, 0:50] + 2 zero pads
    float  bias[4];

    const float* __restrict__ xb = x + (size_t)b * kT * kF;

#pragma unroll
    for (int r = 0; r < 4; ++r) {
        const int row = jj + r * kH;
        const float4* wr = (const float4*)(W_ih + row * kF);   // 160B rows, 16B aligned
#pragma unroll
        for (int q = 0; q < 10; ++q) wih[r][q] = wr[q];
        const float2* hr = (const float2*)(W_hh + row * kH);   // 200B rows, 8B aligned
#pragma unroll
        for (int q = 0; q < 12; ++q) {
            float2 a = hr[2 * q], c2 = hr[2 * q + 1];
            whh[r][q] = make_float4(a.x, a.y, c2.x, c2.y);
        }
        {
            float2 a = hr[24];
            whh[r][12] = make_float4(a.x, a.y, 0.f, 0.f);
        }
        bias[r] = b_ih[row] + b_hh[row];
    }

    // init: h0 = 0; c0 = 0 except unit 0 -> 1
    if (j < 52) sh_h[j] = 0.f;
    float c = (j == 0) ? 1.f : 0.f;

    // stage x[b,0,:]
    if (j < 10) ((float4*)sh_x[0])[j] = ((const float4*)xb)[j];

    float4 px = make_float4(0.f, 0.f, 0.f, 0.f);

    for (int t = 0; t < kT; ++t) {
        const int cur = t & 1;

        // prefetch x[b,t+1,:] (lanes 0..9) while FMAs run
        if (j < 10 && (t + 1) < kT) {
            px = ((const float4*)(xb + (size_t)(t + 1) * kF))[j];
        }

        float a0 = bias[0], a1 = bias[1], a2 = bias[2], a3 = bias[3];

        const float4* xv = (const float4*)sh_x[cur];
#pragma unroll
        for (int q = 0; q < 10; ++q) {            // x part: 4 rows x 40
            float4 v = xv[q];                      // broadcast LDS read, 16 FMAs
            a0 = fmaf(v.x, wih[0][q].x, a0); a0 = fmaf(v.y, wih[0][q].y, a0);
            a0 = fmaf(v.z, wih[0][q].z, a0); a0 = fmaf(v.w, wih[0][q].w, a0);
            a1 = fmaf(v.x, wih[1][q].x, a1); a1 = fmaf(v.y, wih[1][q].y, a1);
            a1 = fmaf(v.z, wih[1][q].z, a1); a1 = fmaf(v.w, wih[1][q].w, a1);
            a2 = fmaf(v.x, wih[2][q].x, a2); a2 = fmaf(v.y, wih[2][q].y, a2);
            a2 = fmaf(v.z, wih[2][q].z, a2); a2 = fmaf(v.w, wih[2][q].w, a2);
            a3 = fmaf(v.x, wih[3][q].x, a3); a3 = fmaf(v.y, wih[3][q].y, a3);
            a3 = fmaf(v.z, wih[3][q].z, a3); a3 = fmaf(v.w, wih[3][q].w, a3);
        }
        const float4* hv = (const float4*)sh_h;
#pragma unroll
        for (int q = 0; q < 13; ++q) {            // h part: 4 rows x 52(padded)
            float4 v = hv[q];                      // broadcast LDS read, 16 FMAs
            a0 = fmaf(v.x, whh[0][q].x, a0); a0 = fmaf(v.y, whh[0][q].y, a0);
            a0 = fmaf(v.z, whh[0][q].z, a0); a0 = fmaf(v.w, whh[0][q].w, a0);
            a1 = fmaf(v.x, whh[1][q].x, a1); a1 = fmaf(v.y, whh[1][q].y, a1);
            a1 = fmaf(v.z, whh[1][q].z, a1); a1 = fmaf(v.w, whh[1][q].w, a1);
            a2 = fmaf(v.x, whh[2][q].x, a2); a2 = fmaf(v.y, whh[2][q].y, a2);
            a2 = fmaf(v.z, whh[2][q].z, a2); a2 = fmaf(v.w, whh[2][q].w, a2);
            a3 = fmaf(v.x, whh[3][q].x, a3); a3 = fmaf(v.y, whh[3][q].y, a3);
            a3 = fmaf(v.z, whh[3][q].z, a3); a3 = fmaf(v.w, whh[3][q].w, a3);
        }

        // thread-local cell update (i,f,g,o all in this thread; c in register)
        float i_s = fast_sigmoid(a0);
        float f_s = fast_sigmoid(a1);
        float g_t = fast_tanh(a2);
        float o_s = fast_sigmoid(a3);
        c = fmaf(f_s, c, i_s * g_t);
        float hval = o_s * fast_tanh(c);
        if (j < kH) sh_h[j] = hval;               // wave-synchronous: no barrier

        // commit prefetched x into the other buffer
        if (j < 10 && (t + 1) < kT) {
            ((float4*)sh_x[cur ^ 1])[j] = px;
        }
    }

    // head: relu(h @ W1.T + b1) @ W2.T + b2 + x[b, T-1, 0]
    if (j < 10) {
        float acc = b1[j];
#pragma unroll
        for (int k = 0; k < kH; ++k) acc = fmaf(sh_h[k], W1[j * kH + k], acc);
        sh_head[j] = fmaxf(acc, 0.f);
    }
    if (j == 0) {
        float acc = b2[0];
#pragma unroll
        for (int u = 0; u < 10; ++u) acc = fmaf(sh_head[u], W2[u], acc);
        out[b] = acc + xb[(kT - 1) * kF];         // + x[b, 511, 0]
    }
}

extern "C" void kernel_launch(void* const* d_in, const int* in_sizes, int n_in,
                              void* d_out, int out_size, void* d_ws, size_t ws_size,
                              hipStream_t stream) {
    const float* x    = (const float*)d_in[0];
    const float* W_ih = (const float*)d_in[1];
    const float* W_hh = (const float*)d_in[2];
    const float* b_ih = (const float*)d_in[3];
    const float* b_hh = (const float*)d_in[4];
    const float* W1   = (const float*)d_in[5];
    const float* b1   = (const float*)d_in[6];
    const float* W2   = (const float*)d_in[7];
    const float* b2   = (const float*)d_in[8];
    float* out = (float*)d_out;

    lstm_unitwise<<<dim3(kB), dim3(64), 0, stream>>>(
        x, W_ih, W_hh, b_ih, b_hh, W1, b1, W2, b2, out);
}

// Round 4
// 505.880 us; speedup vs baseline: 1.6514x; 1.6514x over previous
//
#include <hip/hip_runtime.h>

// LSTM: B=1024, T=512, F=40, H=50, fp32. One block (128 threads = 2 waves)
// per batch element; 512 sequential steps in-block.
// Thread t (t<100) owns gate rows t and t+100 (2 rows/thread), so each
// broadcast LDS read of the x|h panel feeds 8 FMAs and a batch-step costs
// only 2 waves x 23 = 46 broadcast ds_read_b128 (r2: 92; r2 was LDS-bound
// at ~6.5 cyc per broadcast b128 on the per-CU LDS pipe).
// Weights: 184 floats/thread -> ~210 regs; waves_per_eu(2,2) sets a 256-reg
// budget (2 waves/SIMD, 8 waves/CU, 4 blocks/CU) so weights stay in arch
// VGPRs (r1/r2 failure: 128-budget forced AGPR spill; r3: 512-budget/1 wave
// had no latency hiding + massive AGPR copy inflation).

constexpr int kB = 1024;
constexpr int kT = 512;
constexpr int kF = 40;
constexpr int kH = 50;

__device__ __forceinline__ float fast_sigmoid(float v) {
    return __builtin_amdgcn_rcpf(1.f + __expf(-v));
}
__device__ __forceinline__ float fast_tanh(float v) {
    return 1.f - 2.f * __builtin_amdgcn_rcpf(__expf(2.f * v) + 1.f);
}

__global__ __attribute__((amdgpu_flat_work_group_size(128, 128),
                          amdgpu_waves_per_eu(2, 2)))
void lstm_2row(
    const float* __restrict__ x,      // [B,T,F]
    const float* __restrict__ W_ih,   // [4H,F]
    const float* __restrict__ W_hh,   // [4H,H]
    const float* __restrict__ b_ih,   // [4H]
    const float* __restrict__ b_hh,   // [4H]
    const float* __restrict__ W1,     // [10,H]
    const float* __restrict__ b1,     // [10]
    const float* __restrict__ W2,     // [1,10]
    const float* __restrict__ b2,     // [1]
    float* __restrict__ out)          // [B]
{
    const int b   = blockIdx.x;
    const int tid = threadIdx.x;
    const int gt  = (tid < 100) ? tid : 99;   // clamped gate-thread id (no OOB)

    __shared__ __align__(16) float sh_h[52];     // h state (50 + 2 pad)
    __shared__ __align__(16) float sh_x[2][40];  // double-buffered x_t
    __shared__ __align__(16) float sh_pre[200];  // gate pre-activations
    __shared__ float sh_head[10];

    // Per-thread weights: rows gt and gt+100.
    float4 wih[2][10];   // W_ih[row, 0:40]
    float4 whh[2][13];   // W_hh[row, 0:50] + 2 zero pads
    float  bias[2];

    const float* __restrict__ xb = x + (size_t)b * kT * kF;

#pragma unroll
    for (int r = 0; r < 2; ++r) {
        const int row = gt + r * 100;
        const float4* wr = (const float4*)(W_ih + row * kF);   // 160B rows, 16B aligned
#pragma unroll
        for (int q = 0; q < 10; ++q) wih[r][q] = wr[q];
        const float2* hr = (const float2*)(W_hh + row * kH);   // 200B rows, 8B aligned
#pragma unroll
        for (int q = 0; q < 12; ++q) {
            float2 a = hr[2 * q], c2 = hr[2 * q + 1];
            whh[r][q] = make_float4(a.x, a.y, c2.x, c2.y);
        }
        {
            float2 a = hr[24];
            whh[r][12] = make_float4(a.x, a.y, 0.f, 0.f);
        }
        bias[r] = b_ih[row] + b_hh[row];
    }

    // init: h0 = 0; c0 = 0 except unit 0 -> 1
    if (tid < 52) sh_h[tid] = 0.f;
    float c = (tid == 0) ? 1.f : 0.f;

    // stage x[b,0,:]
    if (tid < 10) ((float4*)sh_x[0])[tid] = ((const float4*)xb)[tid];
    __syncthreads();

    float4 px = make_float4(0.f, 0.f, 0.f, 0.f);

    for (int t = 0; t < kT; ++t) {
        const int cur = t & 1;

        // prefetch x[b,t+1,:] (lanes 100..109, wave 1) while FMAs run
        if (tid >= 100 && tid < 110 && (t + 1) < kT) {
            px = ((const float4*)(xb + (size_t)(t + 1) * kF))[tid - 100];
        }

        float a0 = bias[0], a1 = bias[1];

        const float4* xv = (const float4*)sh_x[cur];
#pragma unroll
        for (int q = 0; q < 10; ++q) {            // x part: 2 rows x 40
            float4 v = xv[q];                      // broadcast LDS read -> 8 FMAs
            a0 = fmaf(v.x, wih[0][q].x, a0); a0 = fmaf(v.y, wih[0][q].y, a0);
            a0 = fmaf(v.z, wih[0][q].z, a0); a0 = fmaf(v.w, wih[0][q].w, a0);
            a1 = fmaf(v.x, wih[1][q].x, a1); a1 = fmaf(v.y, wih[1][q].y, a1);
            a1 = fmaf(v.z, wih[1][q].z, a1); a1 = fmaf(v.w, wih[1][q].w, a1);
        }
        const float4* hv = (const float4*)sh_h;
#pragma unroll
        for (int q = 0; q < 13; ++q) {            // h part: 2 rows x 52(padded)
            float4 v = hv[q];                      // broadcast LDS read -> 8 FMAs
            a0 = fmaf(v.x, whh[0][q].x, a0); a0 = fmaf(v.y, whh[0][q].y, a0);
            a0 = fmaf(v.z, whh[0][q].z, a0); a0 = fmaf(v.w, whh[0][q].w, a0);
            a1 = fmaf(v.x, whh[1][q].x, a1); a1 = fmaf(v.y, whh[1][q].y, a1);
            a1 = fmaf(v.z, whh[1][q].z, a1); a1 = fmaf(v.w, whh[1][q].w, a1);
        }
        if (tid < 100) {
            sh_pre[tid]       = a0;   // rows 0..99   (i | f gates)
            sh_pre[tid + 100] = a1;   // rows 100..199 (g | o gates)
        }
        __syncthreads();

        // cell update: thread u < 50 owns hidden unit u (c in register)
        if (tid < kH) {
            float gi = sh_pre[tid];
            float gf = sh_pre[tid + kH];
            float gg = sh_pre[tid + 2 * kH];
            float go = sh_pre[tid + 3 * kH];
            float i_s = fast_sigmoid(gi);
            float f_s = fast_sigmoid(gf);
            float g_t = fast_tanh(gg);
            float o_s = fast_sigmoid(go);
            c = fmaf(f_s, c, i_s * g_t);
            sh_h[tid] = o_s * fast_tanh(c);
        }
        // commit prefetched x into the other buffer
        if (tid >= 100 && tid < 110 && (t + 1) < kT) {
            ((float4*)sh_x[cur ^ 1])[tid - 100] = px;
        }
        __syncthreads();
    }

    // head: relu(h @ W1.T + b1) @ W2.T + b2 + x[b, T-1, 0]
    if (tid < 10) {
        float acc = b1[tid];
#pragma unroll
        for (int k = 0; k < kH; ++k) acc = fmaf(sh_h[k], W1[tid * kH + k], acc);
        sh_head[tid] = fmaxf(acc, 0.f);
    }
    __syncthreads();
    if (tid == 0) {
        float acc = b2[0];
#pragma unroll
        for (int u = 0; u < 10; ++u) acc = fmaf(sh_head[u], W2[u], acc);
        out[b] = acc + xb[(kT - 1) * kF];         // + x[b, 511, 0]
    }
}

extern "C" void kernel_launch(void* const* d_in, const int* in_sizes, int n_in,
                              void* d_out, int out_size, void* d_ws, size_t ws_size,
                              hipStream_t stream) {
    const float* x    = (const float*)d_in[0];
    const float* W_ih = (const float*)d_in[1];
    const float* W_hh = (const float*)d_in[2];
    const float* b_ih = (const float*)d_in[3];
    const float* b_hh = (const float*)d_in[4];
    const float* W1   = (const float*)d_in[5];
    const float* b1   = (const float*)d_in[6];
    const float* W2   = (const float*)d_in[7];
    const float* b2   = (const float*)d_in[8];
    float* out = (float*)d_out;

    lstm_2row<<<dim3(kB), dim3(128), 0, stream>>>(
        x, W_ih, W_hh, b_ih, b_hh, W1, b1, W2, b2, out);
}